// Round 4
// baseline (20902.570 us; speedup 1.0000x reference)
//
#include <hip/hip_runtime.h>
#include <stdint.h>
#include <math.h>

#define SEQ   4096
#define INDIM 1024
#define HID   1024
#define GCOLS 4096   // 4 gates * HID

// =================== Phase 1: Xp[t][g*1024+j] = bias_g[j] + sum_k batch[t][k]*Wg[k][j]
// fp32 vector GEMM, 128x128 tile, 256 threads, 8x8 per thread, BK=8. (unchanged, ~0.4ms)
__global__ __launch_bounds__(256) void xproj_gemm(
    const float* __restrict__ batch,
    const float* __restrict__ Wf, const float* __restrict__ Bf,
    const float* __restrict__ Wi, const float* __restrict__ Bi,
    const float* __restrict__ Wm, const float* __restrict__ Bm,
    const float* __restrict__ Wo, const float* __restrict__ Bo,
    float* __restrict__ Xp)
{
    __shared__ float As[8][128];
    __shared__ float Bs[8][128];

    const int bx = blockIdx.x;          // 0..31 : col block (gate = bx>>3)
    const int by = blockIdx.y;          // 0..31 : row block
    const int gate = bx >> 3;
    const int cb = (bx & 7) * 128;      // col base within gate

    const float* W; const float* Bv;
    if      (gate == 0) { W = Wf; Bv = Bf; }
    else if (gate == 1) { W = Wi; Bv = Bi; }
    else if (gate == 2) { W = Wm; Bv = Bm; }
    else                { W = Wo; Bv = Bo; }

    const int t  = threadIdx.x;
    const int tx = t & 15;
    const int ty = t >> 4;
    const int arow = t >> 1;            // 0..127
    const int akc  = (t & 1) * 4;       // 0 or 4
    const int bkk  = t >> 5;            // 0..7
    const int bc4  = (t & 31) * 4;      // 0..124

    float acc[8][8];
#pragma unroll
    for (int r = 0; r < 8; ++r)
#pragma unroll
        for (int c = 0; c < 8; ++c) acc[r][c] = 0.f;

    const float* aptr = batch + (size_t)(by * 128 + arow) * INDIM + akc;
    const float* bptr = W + (size_t)bkk * HID + cb + bc4;

    for (int k0 = 0; k0 < INDIM; k0 += 8) {
        float4 av = *(const float4*)(aptr + k0);
        float4 bv = *(const float4*)(bptr + (size_t)k0 * HID);
        __syncthreads();
        As[akc + 0][arow] = av.x;
        As[akc + 1][arow] = av.y;
        As[akc + 2][arow] = av.z;
        As[akc + 3][arow] = av.w;
        *(float4*)&Bs[bkk][bc4] = bv;
        __syncthreads();
#pragma unroll
        for (int kk = 0; kk < 8; ++kk) {
            float a[8], b[8];
            *(float4*)&a[0] = *(const float4*)&As[kk][ty * 8];
            *(float4*)&a[4] = *(const float4*)&As[kk][ty * 8 + 4];
            *(float4*)&b[0] = *(const float4*)&Bs[kk][tx * 8];
            *(float4*)&b[4] = *(const float4*)&Bs[kk][tx * 8 + 4];
#pragma unroll
            for (int r = 0; r < 8; ++r)
#pragma unroll
                for (int c = 0; c < 8; ++c)
                    acc[r][c] = fmaf(a[r], b[c], acc[r][c]);
        }
    }

    float bias[8];
    *(float4*)&bias[0] = *(const float4*)(Bv + cb + tx * 8);
    *(float4*)&bias[4] = *(const float4*)(Bv + cb + tx * 8 + 4);

#pragma unroll
    for (int r = 0; r < 8; ++r) {
        float4 o0, o1;
        o0.x = acc[r][0] + bias[0]; o0.y = acc[r][1] + bias[1];
        o0.z = acc[r][2] + bias[2]; o0.w = acc[r][3] + bias[3];
        o1.x = acc[r][4] + bias[4]; o1.y = acc[r][5] + bias[5];
        o1.z = acc[r][6] + bias[6]; o1.w = acc[r][7] + bias[7];
        float* dst = Xp + (size_t)(by * 128 + ty * 8 + r) * GCOLS + gate * HID + cb + tx * 8;
        *(float4*)(dst)     = o0;
        *(float4*)(dst + 4) = o1;
    }
}

// =================== Phase 2: 512 blocks x 64 threads (1 wave), block j owns
// columns j and j+512. No LDS, no __syncthreads. Lane l polls h[k] for
// k = 128*i + 2*l (+1), i=0..7 (16 packed u64: tag<<32 | float bits) — the
// polled values ARE the MAC inputs. Weights (128 floats/lane) pinned in VGPRs
// via asm keep-alive (round-3 counters showed VGPR_Count=56 => compiler had
// rematerialized the loads into the loop, re-reading 64KB/block/step from L2).
// Reduce: 7-level fold+butterfly (10 shfls) lands (col,gate)=(l>>2&1, l&3) in
// lanes 0..7; activations run in parallel on those lanes; lanes 0/4 hold cell
// state, publish, and write out. Double-buffered hb => overwrite-safe.
__global__ __launch_bounds__(64, 1) void lstm_rec(
    const float* __restrict__ Wf, const float* __restrict__ Wi,
    const float* __restrict__ Wm, const float* __restrict__ Wo,
    const float* __restrict__ Xp,
    unsigned long long* __restrict__ hb,   // 2 x 1024 packed (tag,val)
    float* __restrict__ out)
{
    const int j = blockIdx.x;      // 0..511 : columns j and j+512
    const int l = threadIdx.x;     // 0..63

    // publish h^(0)=0 with tag 1 into buffer 0 FIRST (before slow weight fill)
    if (l == 0) {
        __hip_atomic_store(&hb[j],       1ull << 32, __ATOMIC_RELAXED, __HIP_MEMORY_SCOPE_AGENT);
        __hip_atomic_store(&hb[j + 512], 1ull << 32, __ATOMIC_RELAXED, __HIP_MEMORY_SCOPE_AGENT);
    }

    const float* Wg[4] = { Wf, Wi, Wm, Wo };

    // wr[i][g][c][r] = Wg[(INDIM + 128*i + 2*l + r)*HID + (j + 512*c)]
    float wr[8][4][2][2];
#pragma unroll
    for (int i = 0; i < 8; ++i)
#pragma unroll
        for (int g = 0; g < 4; ++g) {
            const float* base = Wg[g] + (size_t)(INDIM + 128 * i + 2 * l) * HID + j;
            wr[i][g][0][0] = base[0];
            wr[i][g][0][1] = base[HID];
            wr[i][g][1][0] = base[512];
            wr[i][g][1][1] = base[HID + 512];
        }
    // pin: make each value asm-defined so the loads cannot be rematerialized
#pragma unroll
    for (int i = 0; i < 8; ++i)
#pragma unroll
        for (int g = 0; g < 4; ++g)
#pragma unroll
            for (int c = 0; c < 2; ++c)
#pragma unroll
                for (int r = 0; r < 2; ++r)
                    asm volatile("" : "+v"(wr[i][g][c][r]));

    float cst = 0.f;               // cell state (lanes 0 and 4 only)
    int budget = 1 << 20;          // poll budget: bug => wrong answer, not hang

    for (int s = 0; s < SEQ; ++s) {
        const unsigned long long* src = hb + (size_t)(s & 1) * 1024;
        unsigned long long*       dst = hb + (size_t)((s + 1) & 1) * 1024;
        const unsigned int tg = (unsigned int)(s + 1);

        // prefetch Xp (independent of h): lane pattern repeats every 8 lanes
        const int col = j + (((l >> 2) & 1) << 9);
        float xp = Xp[(size_t)s * GCOLS + (size_t)(l & 3) * HID + col];

        // spin until all 16 of this lane's h values carry this step's tag
        unsigned long long v[16];
        for (;;) {
#pragma unroll
            for (int i = 0; i < 8; ++i) {
                v[2 * i]     = __hip_atomic_load(&src[128 * i + 2 * l],     __ATOMIC_RELAXED, __HIP_MEMORY_SCOPE_AGENT);
                v[2 * i + 1] = __hip_atomic_load(&src[128 * i + 2 * l + 1], __ATOMIC_RELAXED, __HIP_MEMORY_SCOPE_AGENT);
            }
            unsigned int bad = 0;
#pragma unroll
            for (int q = 0; q < 16; ++q) bad |= ((unsigned int)(v[q] >> 32)) ^ tg;
            if (__all(bad == 0)) break;
            if (--budget < 0) break;
        }

        // MAC: 16 k-values x {2 cols x 4 gates} against register weights
        float aa[4] = {0.f, 0.f, 0.f, 0.f};   // col j     gates f,i,m,o
        float ab[4] = {0.f, 0.f, 0.f, 0.f};   // col j+512 gates f,i,m,o
#pragma unroll
        for (int i = 0; i < 8; ++i) {
            float h0 = __uint_as_float((unsigned int)v[2 * i]);
            float h1 = __uint_as_float((unsigned int)v[2 * i + 1]);
#pragma unroll
            for (int g = 0; g < 4; ++g) {
                aa[g] = fmaf(h0, wr[i][g][0][0], aa[g]);
                aa[g] = fmaf(h1, wr[i][g][0][1], aa[g]);
                ab[g] = fmaf(h0, wr[i][g][1][0], ab[g]);
                ab[g] = fmaf(h1, wr[i][g][1][1], ab[g]);
            }
        }

        // ---- reduce 8 partials -> lane (l&7) owns (col=(l>>2)&1, gate=l&3)
        const bool b0 = (l & 1) != 0;
        float xA = (b0 ? aa[1] : aa[0]) + __shfl_xor(b0 ? aa[0] : aa[1], 1, 64); // colA gate l&1
        float yA = (b0 ? aa[3] : aa[2]) + __shfl_xor(b0 ? aa[2] : aa[3], 1, 64); // colA gate (l&1)+2
        float xB = (b0 ? ab[1] : ab[0]) + __shfl_xor(b0 ? ab[0] : ab[1], 1, 64);
        float yB = (b0 ? ab[3] : ab[2]) + __shfl_xor(b0 ? ab[2] : ab[3], 1, 64);
        const bool b1 = (l & 2) != 0;
        float zA = (b1 ? yA : xA) + __shfl_xor(b1 ? xA : yA, 2, 64);             // colA gate l&3
        float zB = (b1 ? yB : xB) + __shfl_xor(b1 ? xB : yB, 2, 64);             // colB gate l&3
        const bool b2 = (l & 4) != 0;
        float zz = (b2 ? zB : zA) + __shfl_xor(b2 ? zA : zB, 4, 64);             // (col,gate)=(l>>2&1,l&3)
#pragma unroll
        for (int m = 8; m < 64; m <<= 1) zz += __shfl_xor(zz, m, 64);

        // ---- parallel activations (uniform code, no branch):
        // gates f,i,o: sigmoid(x); gate m: tanh(x) = 2*sigmoid(2x)-1
        float pre = zz + xp;
        const bool isM = ((l & 3) == 2);
        float arg = isM ? 2.f * pre : pre;
        float e = expf(-arg);
        float S = 1.f / (1.f + e);
        float A = isM ? 2.f * S - 1.f : S;

        // gather i,m,o acts to lanes 0 (colA) and 4 (colB)
        const int gb = l & 60;
        float i_ = __shfl(A, gb + 1, 64);
        float m_ = __shfl(A, gb + 2, 64);
        float o_ = __shfl(A, gb + 3, 64);

        if ((l & 3) == 0 && l < 8) {   // lanes 0 and 4
            cst = fmaf(A, cst, i_ * m_);               // A = own forget-gate act
            float e2 = expf(-2.f * cst);
            float th = 2.f / (1.f + e2) - 1.f;         // tanh, NaN-safe at +-inf
            float hv = o_ * th;
            out[(size_t)s * HID + col] = hv;           // col: lane0 -> j, lane4 -> j+512
            __hip_atomic_store(&dst[col],
                               ((unsigned long long)(tg + 1) << 32) |
                               (unsigned long long)__float_as_uint(hv),
                               __ATOMIC_RELAXED, __HIP_MEMORY_SCOPE_AGENT);
        }
    }
}

extern "C" void kernel_launch(void* const* d_in, const int* in_sizes, int n_in,
                              void* d_out, int out_size, void* d_ws, size_t ws_size,
                              hipStream_t stream) {
    const float* batch = (const float*)d_in[0];
    const float* Wf = (const float*)d_in[1]; const float* Bf = (const float*)d_in[2];
    const float* Wi = (const float*)d_in[3]; const float* Bi = (const float*)d_in[4];
    const float* Wm = (const float*)d_in[5]; const float* Bm = (const float*)d_in[6];
    const float* Wo = (const float*)d_in[7]; const float* Bo = (const float*)d_in[8];
    float* out = (float*)d_out;

    float* Xp = (float*)d_ws;                                   // 64 MB
    unsigned long long* hb =
        (unsigned long long*)((char*)d_ws + (size_t)SEQ * GCOLS * sizeof(float)); // 16 KB

    xproj_gemm<<<dim3(32, 32), 256, 0, stream>>>(batch, Wf, Bf, Wi, Bi, Wm, Bm, Wo, Bo, Xp);

    // 512 one-wave blocks, 2/CU: co-resident by construction; no grid sync needed.
    lstm_rec<<<dim3(512), 64, 0, stream>>>(Wf, Wi, Wm, Wo, Xp, hb, out);
}

// Round 5
// 12409.167 us; speedup vs baseline: 1.6844x; 1.6844x over previous
//
#include <hip/hip_runtime.h>
#include <stdint.h>
#include <math.h>

#define SEQ   4096
#define INDIM 1024
#define HID   1024
#define GCOLS 4096   // 4 gates * HID

// =================== Phase 1: Xp[t][g*1024+j] = bias_g[j] + sum_k batch[t][k]*Wg[k][j]
// fp32 vector GEMM, 128x128 tile, 256 threads, 8x8 per thread, BK=8. (unchanged)
__global__ __launch_bounds__(256) void xproj_gemm(
    const float* __restrict__ batch,
    const float* __restrict__ Wf, const float* __restrict__ Bf,
    const float* __restrict__ Wi, const float* __restrict__ Bi,
    const float* __restrict__ Wm, const float* __restrict__ Bm,
    const float* __restrict__ Wo, const float* __restrict__ Bo,
    float* __restrict__ Xp)
{
    __shared__ float As[8][128];
    __shared__ float Bs[8][128];

    const int bx = blockIdx.x;          // 0..31 : col block (gate = bx>>3)
    const int by = blockIdx.y;          // 0..31 : row block
    const int gate = bx >> 3;
    const int cb = (bx & 7) * 128;      // col base within gate

    const float* W; const float* Bv;
    if      (gate == 0) { W = Wf; Bv = Bf; }
    else if (gate == 1) { W = Wi; Bv = Bi; }
    else if (gate == 2) { W = Wm; Bv = Bm; }
    else                { W = Wo; Bv = Bo; }

    const int t  = threadIdx.x;
    const int tx = t & 15;
    const int ty = t >> 4;
    const int arow = t >> 1;            // 0..127
    const int akc  = (t & 1) * 4;       // 0 or 4
    const int bkk  = t >> 5;            // 0..7
    const int bc4  = (t & 31) * 4;      // 0..124

    float acc[8][8];
#pragma unroll
    for (int r = 0; r < 8; ++r)
#pragma unroll
        for (int c = 0; c < 8; ++c) acc[r][c] = 0.f;

    const float* aptr = batch + (size_t)(by * 128 + arow) * INDIM + akc;
    const float* bptr = W + (size_t)bkk * HID + cb + bc4;

    for (int k0 = 0; k0 < INDIM; k0 += 8) {
        float4 av = *(const float4*)(aptr + k0);
        float4 bv = *(const float4*)(bptr + (size_t)k0 * HID);
        __syncthreads();
        As[akc + 0][arow] = av.x;
        As[akc + 1][arow] = av.y;
        As[akc + 2][arow] = av.z;
        As[akc + 3][arow] = av.w;
        *(float4*)&Bs[bkk][bc4] = bv;
        __syncthreads();
#pragma unroll
        for (int kk = 0; kk < 8; ++kk) {
            float a[8], b[8];
            *(float4*)&a[0] = *(const float4*)&As[kk][ty * 8];
            *(float4*)&a[4] = *(const float4*)&As[kk][ty * 8 + 4];
            *(float4*)&b[0] = *(const float4*)&Bs[kk][tx * 8];
            *(float4*)&b[4] = *(const float4*)&Bs[kk][tx * 8 + 4];
#pragma unroll
            for (int r = 0; r < 8; ++r)
#pragma unroll
                for (int c = 0; c < 8; ++c)
                    acc[r][c] = fmaf(a[r], b[c], acc[r][c]);
        }
    }

    float bias[8];
    *(float4*)&bias[0] = *(const float4*)(Bv + cb + tx * 8);
    *(float4*)&bias[4] = *(const float4*)(Bv + cb + tx * 8 + 4);

#pragma unroll
    for (int r = 0; r < 8; ++r) {
        float4 o0, o1;
        o0.x = acc[r][0] + bias[0]; o0.y = acc[r][1] + bias[1];
        o0.z = acc[r][2] + bias[2]; o0.w = acc[r][3] + bias[3];
        o1.x = acc[r][4] + bias[4]; o1.y = acc[r][5] + bias[5];
        o1.z = acc[r][6] + bias[6]; o1.w = acc[r][7] + bias[7];
        float* dst = Xp + (size_t)(by * 128 + ty * 8 + r) * GCOLS + gate * HID + cb + tx * 8;
        *(float4*)(dst)     = o0;
        *(float4*)(dst + 4) = o1;
    }
}

// =================== Phase 2: 256 blocks x 256 threads (4 waves). Block b owns
// cols 4b..4b+3. Wave w polls h-slice k in [256w,256w+256): lane l polls the 4
// contiguous u64 at kq=256w+4l — and those ARE its MAC inputs (no LDS h-stage,
// no stage barrier; round-3's 6.7e7 LDS bank conflicts eliminated). Each lane
// accumulates 16 sums (4 gates x 4 cols) over its 4 k's, folds 16->1 with 15
// select-exchange shfls + 2 butterflies (lane l<16 owns (g,c)=(l>>2,l&3) for
// its wave's slice), one gsum LDS write + single barrier, then 16-lane
// PARALLEL activations (round 3 had 4 serial expf chains on one lane).
// gsum double-buffered by step parity => no tail race, no second barrier.
// h published as packed (tag<<32)|bits, agent-scope relaxed atomics;
// double-buffered hb => overwrite-safe (writer at step s overwrites data whose
// every consumer finished reading at step s-1 — gated through the tag chain).
// s_sleep between failed poll rounds cuts LLC coherent-load contention.
__global__ __launch_bounds__(256, 1) void lstm_rec(
    const float* __restrict__ Wf, const float* __restrict__ Wi,
    const float* __restrict__ Wm, const float* __restrict__ Wo,
    const float* __restrict__ Xp,
    unsigned long long* __restrict__ hb,   // 2 x 1024 packed (tag,val)
    float* __restrict__ out)
{
    const int b = blockIdx.x;      // 0..255
    const int t = threadIdx.x;     // 0..255
    const int w = t >> 6;          // wave id = k-slice id
    const int l = t & 63;          // lane
    const int j4 = b * 4;

    __shared__ float gsum[2][4][16];   // [step parity][wave][4g+c]

    // publish h^(0)=0 with tag 1 into buffer 0 FIRST (before slow weight fill)
    if (t < 4)
        __hip_atomic_store(&hb[j4 + t], 1ull << 32,
                           __ATOMIC_RELAXED, __HIP_MEMORY_SCOPE_AGENT);

    const int kq = w * 256 + l * 4;    // this lane's 4 h-indices == its MAC k's

    // weights wr[q][4g+c] = W_h^g[kq+q][j4+c]  (64 floats/lane; round-3
    // evidence: compiler holds these in the unified VGPR/AGPR file fine)
    const float* Wg[4] = { Wf, Wi, Wm, Wo };
    float wr[4][16];
#pragma unroll
    for (int g = 0; g < 4; ++g)
#pragma unroll
        for (int q = 0; q < 4; ++q) {
            float4 v4 = *(const float4*)(Wg[g] + (size_t)(INDIM + kq + q) * HID + j4);
            wr[q][4 * g + 0] = v4.x; wr[q][4 * g + 1] = v4.y;
            wr[q][4 * g + 2] = v4.z; wr[q][4 * g + 3] = v4.w;
        }

    float cst = 0.f;               // cell state (lanes t<4 only)
    int budget = 1 << 20;          // cumulative poll budget: bug => wrong answer, not hang

    for (int s = 0; s < SEQ; ++s) {
        const unsigned long long* src = hb + (size_t)(s & 1) * 1024;
        unsigned long long*       dst = hb + (size_t)((s + 1) & 1) * 1024;
        const unsigned int tg = (unsigned int)(s + 1);

        // prefetch Xp (independent of h): lane t<16 -> gate t>>2, col j4+(t&3)
        float xp = 0.f;
        if (t < 16) xp = Xp[(size_t)s * GCOLS + (size_t)(t >> 2) * HID + j4 + (t & 3)];

        // spin until this lane's 4 h values carry this step's tag
        unsigned long long v0, v1, v2, v3;
        for (;;) {
            v0 = __hip_atomic_load(&src[kq + 0], __ATOMIC_RELAXED, __HIP_MEMORY_SCOPE_AGENT);
            v1 = __hip_atomic_load(&src[kq + 1], __ATOMIC_RELAXED, __HIP_MEMORY_SCOPE_AGENT);
            v2 = __hip_atomic_load(&src[kq + 2], __ATOMIC_RELAXED, __HIP_MEMORY_SCOPE_AGENT);
            v3 = __hip_atomic_load(&src[kq + 3], __ATOMIC_RELAXED, __HIP_MEMORY_SCOPE_AGENT);
            unsigned int bad = ((unsigned int)(v0 >> 32) ^ tg) | ((unsigned int)(v1 >> 32) ^ tg)
                             | ((unsigned int)(v2 >> 32) ^ tg) | ((unsigned int)(v3 >> 32) ^ tg);
            if (__all(bad == 0)) break;
            if (--budget < 0) break;
            __builtin_amdgcn_s_sleep(2);   // ~128cy backoff: cuts LLC poll contention
        }

        const float h0 = __uint_as_float((unsigned int)v0);
        const float h1 = __uint_as_float((unsigned int)v1);
        const float h2 = __uint_as_float((unsigned int)v2);
        const float h3 = __uint_as_float((unsigned int)v3);

        // 16 accumulators: a[4g+c] = sum_q h_q * wr[q][4g+c]
        float a[16];
#pragma unroll
        for (int p = 0; p < 16; ++p)
            a[p] = fmaf(h0, wr[0][p], fmaf(h1, wr[1][p], fmaf(h2, wr[2][p], h3 * wr[3][p])));

        // fold 16 -> 1 acc/lane; lane l ends owning p = l&15 (p bits match lane bits)
        const bool q0 = (l & 1) != 0, q1 = (l & 2) != 0, q2 = (l & 4) != 0, q3 = (l & 8) != 0;
        float B[8];
#pragma unroll
        for (int p2 = 0; p2 < 8; ++p2) {
            float snd = q0 ? a[2 * p2]     : a[2 * p2 + 1];
            float kp  = q0 ? a[2 * p2 + 1] : a[2 * p2];
            B[p2] = kp + __shfl_xor(snd, 1, 64);
        }
        float C[4];
#pragma unroll
        for (int r = 0; r < 4; ++r) {
            float snd = q1 ? B[2 * r]     : B[2 * r + 1];
            float kp  = q1 ? B[2 * r + 1] : B[2 * r];
            C[r] = kp + __shfl_xor(snd, 2, 64);
        }
        float D[2];
#pragma unroll
        for (int u = 0; u < 2; ++u) {
            float snd = q2 ? C[2 * u]     : C[2 * u + 1];
            float kp  = q2 ? C[2 * u + 1] : C[2 * u];
            D[u] = kp + __shfl_xor(snd, 4, 64);
        }
        float snd = q3 ? D[0] : D[1];
        float kp  = q3 ? D[1] : D[0];
        float E = kp + __shfl_xor(snd, 8, 64);
        E += __shfl_xor(E, 16, 64);
        E += __shfl_xor(E, 32, 64);
        // E = slice-sum for (g,c) = ((l&15)>>2, l&3)

        if (l < 16) gsum[s & 1][w][l] = E;
        __syncthreads();   // the step's only barrier

        if (t < 16) {      // wave 0 lanes 0..15: parallel activations
            float pre = gsum[s & 1][0][t] + gsum[s & 1][1][t]
                      + gsum[s & 1][2][t] + gsum[s & 1][3][t] + xp;
            const bool isM = ((t >> 2) == 2);              // gate m = tanh
            float arg = isM ? 2.f * pre : pre;
            float e = expf(-arg);
            float S = 1.f / (1.f + e);
            float A = isM ? 2.f * S - 1.f : S;             // tanh(x)=2*sig(2x)-1

            float i_ = __shfl(A, 4 + (t & 3), 64);
            float m_ = __shfl(A, 8 + (t & 3), 64);
            float o_ = __shfl(A, 12 + (t & 3), 64);

            if (t < 4) {   // lane t = col t (g=0 -> A is the forget act)
                cst = fmaf(A, cst, i_ * m_);
                float e2 = expf(-2.f * cst);
                float th = 2.f / (1.f + e2) - 1.f;         // tanh, saturates safely
                float hv = o_ * th;
                out[(size_t)s * HID + j4 + t] = hv;
                __hip_atomic_store(&dst[j4 + t],
                                   ((unsigned long long)(tg + 1) << 32) |
                                   (unsigned long long)__float_as_uint(hv),
                                   __ATOMIC_RELAXED, __HIP_MEMORY_SCOPE_AGENT);
            }
        }
        // gsum race-free across steps: double-buffered by (s&1), and any wave's
        // step-(s+2) rewrite of buffer (s&1) is gated (via the tag chain) behind
        // every block's step-s publish, which is after this tail's reads.
    }
}

extern "C" void kernel_launch(void* const* d_in, const int* in_sizes, int n_in,
                              void* d_out, int out_size, void* d_ws, size_t ws_size,
                              hipStream_t stream) {
    const float* batch = (const float*)d_in[0];
    const float* Wf = (const float*)d_in[1]; const float* Bf = (const float*)d_in[2];
    const float* Wi = (const float*)d_in[3]; const float* Bi = (const float*)d_in[4];
    const float* Wm = (const float*)d_in[5]; const float* Bm = (const float*)d_in[6];
    const float* Wo = (const float*)d_in[7]; const float* Bo = (const float*)d_in[8];
    float* out = (float*)d_out;

    float* Xp = (float*)d_ws;                                   // 64 MB
    unsigned long long* hb =
        (unsigned long long*)((char*)d_ws + (size_t)SEQ * GCOLS * sizeof(float)); // 16 KB

    xproj_gemm<<<dim3(32, 32), 256, 0, stream>>>(batch, Wf, Bf, Wi, Bi, Wm, Bm, Wo, Bo, Xp);

    // 256 blocks / 256 CUs at 1 block/CU: co-resident by construction.
    lstm_rec<<<dim3(256), 256, 0, stream>>>(Wf, Wi, Wm, Wo, Xp, hb, out);
}

// Round 10
// 10829.914 us; speedup vs baseline: 1.9301x; 1.1458x over previous
//
#include <hip/hip_runtime.h>
#include <stdint.h>
#include <math.h>

#define SEQ   4096
#define INDIM 1024
#define HID   1024
#define GCOLS 4096   // 4 gates * HID

typedef uint32_t u32x4 __attribute__((ext_vector_type(4)));

// =================== Phase 1: Xp[t][g*1024+j] = bias_g[j] + sum_k batch[t][k]*Wg[k][j]
// fp32 vector GEMM, 128x128 tile, 256 threads, 8x8 per thread, BK=8. (unchanged)
__global__ __launch_bounds__(256) void xproj_gemm(
    const float* __restrict__ batch,
    const float* __restrict__ Wf, const float* __restrict__ Bf,
    const float* __restrict__ Wi, const float* __restrict__ Bi,
    const float* __restrict__ Wm, const float* __restrict__ Bm,
    const float* __restrict__ Wo, const float* __restrict__ Bo,
    float* __restrict__ Xp)
{
    __shared__ float As[8][128];
    __shared__ float Bs[8][128];

    const int bx = blockIdx.x;          // 0..31 : col block (gate = bx>>3)
    const int by = blockIdx.y;          // 0..31 : row block
    const int gate = bx >> 3;
    const int cb = (bx & 7) * 128;      // col base within gate

    const float* W; const float* Bv;
    if      (gate == 0) { W = Wf; Bv = Bf; }
    else if (gate == 1) { W = Wi; Bv = Bi; }
    else if (gate == 2) { W = Wm; Bv = Bm; }
    else                { W = Wo; Bv = Bo; }

    const int t  = threadIdx.x;
    const int tx = t & 15;
    const int ty = t >> 4;
    const int arow = t >> 1;            // 0..127
    const int akc  = (t & 1) * 4;       // 0 or 4
    const int bkk  = t >> 5;            // 0..7
    const int bc4  = (t & 31) * 4;      // 0..124

    float acc[8][8];
#pragma unroll
    for (int r = 0; r < 8; ++r)
#pragma unroll
        for (int c = 0; c < 8; ++c) acc[r][c] = 0.f;

    const float* aptr = batch + (size_t)(by * 128 + arow) * INDIM + akc;
    const float* bptr = W + (size_t)bkk * HID + cb + bc4;

    for (int k0 = 0; k0 < INDIM; k0 += 8) {
        float4 av = *(const float4*)(aptr + k0);
        float4 bv = *(const float4*)(bptr + (size_t)k0 * HID);
        __syncthreads();
        As[akc + 0][arow] = av.x;
        As[akc + 1][arow] = av.y;
        As[akc + 2][arow] = av.z;
        As[akc + 3][arow] = av.w;
        *(float4*)&Bs[bkk][bc4] = bv;
        __syncthreads();
#pragma unroll
        for (int kk = 0; kk < 8; ++kk) {
            float a[8], b[8];
            *(float4*)&a[0] = *(const float4*)&As[kk][ty * 8];
            *(float4*)&a[4] = *(const float4*)&As[kk][ty * 8 + 4];
            *(float4*)&b[0] = *(const float4*)&Bs[kk][tx * 8];
            *(float4*)&b[4] = *(const float4*)&Bs[kk][tx * 8 + 4];
#pragma unroll
            for (int r = 0; r < 8; ++r)
#pragma unroll
                for (int c = 0; c < 8; ++c)
                    acc[r][c] = fmaf(a[r], b[c], acc[r][c]);
        }
    }

    float bias[8];
    *(float4*)&bias[0] = *(const float4*)(Bv + cb + tx * 8);
    *(float4*)&bias[4] = *(const float4*)(Bv + cb + tx * 8 + 4);

#pragma unroll
    for (int r = 0; r < 8; ++r) {
        float4 o0, o1;
        o0.x = acc[r][0] + bias[0]; o0.y = acc[r][1] + bias[1];
        o0.z = acc[r][2] + bias[2]; o0.w = acc[r][3] + bias[3];
        o1.x = acc[r][4] + bias[4]; o1.y = acc[r][5] + bias[5];
        o1.z = acc[r][6] + bias[6]; o1.w = acc[r][7] + bias[7];
        float* dst = Xp + (size_t)(by * 128 + ty * 8 + r) * GCOLS + gate * HID + cb + tx * 8;
        *(float4*)(dst)     = o0;
        *(float4*)(dst + 4) = o1;
    }
}

// =================== Phase 2: 128 blocks x 256 threads (4 waves). Block b owns
// cols 8b..8b+7. h broadcast as TAGGED FP32: low 8 mantissa bits replaced by
// (step+1)&0xFF (error <= 2^-15 rel ~ 3e-5: negligible; stale tag = tg-2 mod
// 256 != tg; 0xAA poison overwritten long before tag 170 is awaited). One u32
// per h => poll is ONE global_load_dwordx4 sc1 per lane per round (16B, 4
// self-validating words; tearing harmless; sc1 = device scope = LLC-coherent,
// same as __hip_atomic_load AGENT. NOT sc0 sc1 = system scope = HBM).
// Chip-wide poll volume/round: 128 x 4KB = 512KB (r5: 2MB+; r4/r5 evidence:
// step ~ 0.8us floor + volume/~1.4TB/s on the coherent LLC path).
// Wave w polls k-slice [256w,256w+256); lane l holds k=256w+4l..+3, MACs into
// 32 accs (4 gates x 8 cols), 5-level select-exchange fold + butterfly ->
// lane l<32 owns (g,c)=(l>>3,l&7); gsum LDS (parity-buffered), one barrier,
// 32-lane parallel activations, 8 tagged publishes by lanes t<8.
__global__ __launch_bounds__(256, 1) void lstm_rec(
    const float* __restrict__ Wf, const float* __restrict__ Wi,
    const float* __restrict__ Wm, const float* __restrict__ Wo,
    const float* __restrict__ Xp,
    uint32_t* __restrict__ hb,     // 2 x 1024 tagged fp32 words
    float* __restrict__ out)
{
    const int b = blockIdx.x;      // 0..127
    const int t = threadIdx.x;     // 0..255
    const int w = t >> 6;          // wave id = k-slice id
    const int l = t & 63;          // lane
    const int j8 = b * 8;

    __shared__ float gsum[2][4][32];   // [step parity][wave][g*8+c]

    // publish h^(0)=0 with tag 1 into buffer 0 (word 0x1 = denormal ~ 0.0f)
    if (t < 8)
        __hip_atomic_store(&hb[j8 + t], 1u, __ATOMIC_RELAXED, __HIP_MEMORY_SCOPE_AGENT);

    const int kq = w * 256 + l * 4;    // this lane's 4 h-indices == its MAC k's

    // weights wr[q][g][c] = W_h^g[kq+q][j8+c]  (128 floats/lane)
    const float* Wg[4] = { Wf, Wi, Wm, Wo };
    float wr[4][4][8];
#pragma unroll
    for (int g = 0; g < 4; ++g)
#pragma unroll
        for (int q = 0; q < 4; ++q) {
            const float* base = Wg[g] + (size_t)(INDIM + kq + q) * HID + j8;
            *(float4*)&wr[q][g][0] = *(const float4*)(base);
            *(float4*)&wr[q][g][4] = *(const float4*)(base + 4);
        }

    float cst = 0.f;               // cell state (lanes t<8 only)
    int budget = 1 << 20;          // poll budget: bug => wrong answer, not hang

    for (int s = 0; s < SEQ; ++s) {
        const uint32_t* src = hb + (size_t)(s & 1) * 1024;
        uint32_t*       dst = hb + (size_t)((s + 1) & 1) * 1024;
        const uint32_t tg = (uint32_t)(s + 1) & 0xFFu;

        // prefetch Xp (independent of h): lane t<32 -> gate t>>3, col j8+(t&7)
        float xp = 0.f;
        if (t < 32) xp = Xp[(size_t)s * GCOLS + (size_t)(t >> 3) * HID + j8 + (t & 7)];

        // poll: ONE 16B device-scope load per lane per round
        const uint32_t* ap = src + kq;
        uint32_t p0, p1, p2, p3;
        for (;;) {
            u32x4 pv;
            asm volatile("global_load_dwordx4 %0, %1, off sc1\n\t"
                         "s_waitcnt vmcnt(0)"
                         : "=v"(pv) : "v"(ap) : "memory");
            p0 = pv.x; p1 = pv.y; p2 = pv.z; p3 = pv.w;
            uint32_t bad = ((p0 ^ tg) | (p1 ^ tg) | (p2 ^ tg) | (p3 ^ tg)) & 0xFFu;
            if (__all(bad == 0)) break;
            if (--budget < 0) break;
            __builtin_amdgcn_s_sleep(1);   // ~64cy backoff
        }

        const float h0 = __uint_as_float(p0);
        const float h1 = __uint_as_float(p1);
        const float h2 = __uint_as_float(p2);
        const float h3 = __uint_as_float(p3);

        // 32 accumulators: A[g*8+c] = sum_q h_q * wr[q][g][c]
        float A[32];
#pragma unroll
        for (int g = 0; g < 4; ++g)
#pragma unroll
            for (int c = 0; c < 8; ++c)
                A[g * 8 + c] = fmaf(h0, wr[0][g][c],
                               fmaf(h1, wr[1][g][c],
                               fmaf(h2, wr[2][g][c], h3 * wr[3][g][c])));

        // fold 32 -> 1 acc/lane (index bits match lane bits); then butterfly 32
        const bool q0 = (l & 1) != 0, q1 = (l & 2) != 0, q2 = (l & 4) != 0,
                   q3 = (l & 8) != 0, q4 = (l & 16) != 0;
        float B[16];
#pragma unroll
        for (int i = 0; i < 16; ++i) {
            float snd = q0 ? A[2 * i] : A[2 * i + 1];
            float kp  = q0 ? A[2 * i + 1] : A[2 * i];
            B[i] = kp + __shfl_xor(snd, 1, 64);
        }
        float C[8];
#pragma unroll
        for (int i = 0; i < 8; ++i) {
            float snd = q1 ? B[2 * i] : B[2 * i + 1];
            float kp  = q1 ? B[2 * i + 1] : B[2 * i];
            C[i] = kp + __shfl_xor(snd, 2, 64);
        }
        float D[4];
#pragma unroll
        for (int i = 0; i < 4; ++i) {
            float snd = q2 ? C[2 * i] : C[2 * i + 1];
            float kp  = q2 ? C[2 * i + 1] : C[2 * i];
            D[i] = kp + __shfl_xor(snd, 4, 64);
        }
        float E2[2];
#pragma unroll
        for (int i = 0; i < 2; ++i) {
            float snd = q3 ? D[2 * i] : D[2 * i + 1];
            float kp  = q3 ? D[2 * i + 1] : D[2 * i];
            E2[i] = kp + __shfl_xor(snd, 8, 64);
        }
        {
            float snd = q4 ? E2[0] : E2[1];
            float kp  = q4 ? E2[1] : E2[0];
            float E = kp + __shfl_xor(snd, 16, 64);
            E += __shfl_xor(E, 32, 64);
            if (l < 32) gsum[s & 1][w][l] = E;   // lane l owns (g,c)=(l>>3,l&7)
        }
        __syncthreads();   // the step's only barrier

        if (t < 32) {      // wave 0 lanes 0..31: parallel activations
            float pre = gsum[s & 1][0][t] + gsum[s & 1][1][t]
                      + gsum[s & 1][2][t] + gsum[s & 1][3][t] + xp;
            const bool isM = ((t >> 3) == 2);              // gate m = tanh
            float arg = isM ? 2.f * pre : pre;
            float S = 1.f / (1.f + expf(-arg));
            float Aact = isM ? 2.f * S - 1.f : S;          // tanh(x)=2*sig(2x)-1

            float i_ = __shfl(Aact, 8  + (t & 7), 64);
            float m_ = __shfl(Aact, 16 + (t & 7), 64);
            float o_ = __shfl(Aact, 24 + (t & 7), 64);

            if (t < 8) {   // lane t: col j8+t (gate f -> Aact is forget act)
                cst = fmaf(Aact, cst, i_ * m_);
                float th = 2.f / (1.f + expf(-2.f * cst)) - 1.f;  // tanh, NaN-safe
                float hv = o_ * th;
                uint32_t word = (__float_as_uint(hv) & ~0xFFu) | ((tg + 1) & 0xFFu);
                out[(size_t)s * HID + j8 + t] = __uint_as_float(word);
                __hip_atomic_store(&dst[j8 + t], word,
                                   __ATOMIC_RELAXED, __HIP_MEMORY_SCOPE_AGENT);
            }
        }
        // gsum cross-step race-free: parity-buffered; a wave's step-(s+2)
        // rewrite of gsum[s&1] is behind the step-(s+1) barrier, which wave 0
        // reaches only after finishing this tail's reads.
    }
}

extern "C" void kernel_launch(void* const* d_in, const int* in_sizes, int n_in,
                              void* d_out, int out_size, void* d_ws, size_t ws_size,
                              hipStream_t stream) {
    const float* batch = (const float*)d_in[0];
    const float* Wf = (const float*)d_in[1]; const float* Bf = (const float*)d_in[2];
    const float* Wi = (const float*)d_in[3]; const float* Bi = (const float*)d_in[4];
    const float* Wm = (const float*)d_in[5]; const float* Bm = (const float*)d_in[6];
    const float* Wo = (const float*)d_in[7]; const float* Bo = (const float*)d_in[8];
    float* out = (float*)d_out;

    float* Xp = (float*)d_ws;                                   // 64 MB
    uint32_t* hb =
        (uint32_t*)((char*)d_ws + (size_t)SEQ * GCOLS * sizeof(float)); // 8 KB

    xproj_gemm<<<dim3(32, 32), 256, 0, stream>>>(batch, Wf, Bf, Wi, Bi, Wm, Bm, Wo, Bo, Xp);

    // 128 blocks / 256 CUs: co-resident by construction.
    lstm_rec<<<dim3(128), 256, 0, stream>>>(Wf, Wi, Wm, Wo, Xp, hb, out);
}

// Round 11
// 9368.485 us; speedup vs baseline: 2.2312x; 1.1560x over previous
//
#include <hip/hip_runtime.h>
#include <stdint.h>
#include <math.h>

#define SEQ   4096
#define INDIM 1024
#define HID   1024
#define GCOLS 4096   // 4 gates * HID

typedef uint32_t u32x4 __attribute__((ext_vector_type(4)));

// =================== Phase 1: Xp[t][g*1024+j] = bias_g[j] + sum_k batch[t][k]*Wg[k][j]
// fp32 vector GEMM, 128x128 tile, 256 threads, 8x8 per thread, BK=8. (unchanged)
__global__ __launch_bounds__(256) void xproj_gemm(
    const float* __restrict__ batch,
    const float* __restrict__ Wf, const float* __restrict__ Bf,
    const float* __restrict__ Wi, const float* __restrict__ Bi,
    const float* __restrict__ Wm, const float* __restrict__ Bm,
    const float* __restrict__ Wo, const float* __restrict__ Bo,
    float* __restrict__ Xp)
{
    __shared__ float As[8][128];
    __shared__ float Bs[8][128];

    const int bx = blockIdx.x;          // 0..31 : col block (gate = bx>>3)
    const int by = blockIdx.y;          // 0..31 : row block
    const int gate = bx >> 3;
    const int cb = (bx & 7) * 128;      // col base within gate

    const float* W; const float* Bv;
    if      (gate == 0) { W = Wf; Bv = Bf; }
    else if (gate == 1) { W = Wi; Bv = Bi; }
    else if (gate == 2) { W = Wm; Bv = Bm; }
    else                { W = Wo; Bv = Bo; }

    const int t  = threadIdx.x;
    const int tx = t & 15;
    const int ty = t >> 4;
    const int arow = t >> 1;            // 0..127
    const int akc  = (t & 1) * 4;       // 0 or 4
    const int bkk  = t >> 5;            // 0..7
    const int bc4  = (t & 31) * 4;      // 0..124

    float acc[8][8];
#pragma unroll
    for (int r = 0; r < 8; ++r)
#pragma unroll
        for (int c = 0; c < 8; ++c) acc[r][c] = 0.f;

    const float* aptr = batch + (size_t)(by * 128 + arow) * INDIM + akc;
    const float* bptr = W + (size_t)bkk * HID + cb + bc4;

    for (int k0 = 0; k0 < INDIM; k0 += 8) {
        float4 av = *(const float4*)(aptr + k0);
        float4 bv = *(const float4*)(bptr + (size_t)k0 * HID);
        __syncthreads();
        As[akc + 0][arow] = av.x;
        As[akc + 1][arow] = av.y;
        As[akc + 2][arow] = av.z;
        As[akc + 3][arow] = av.w;
        *(float4*)&Bs[bkk][bc4] = bv;
        __syncthreads();
#pragma unroll
        for (int kk = 0; kk < 8; ++kk) {
            float a[8], b[8];
            *(float4*)&a[0] = *(const float4*)&As[kk][ty * 8];
            *(float4*)&a[4] = *(const float4*)&As[kk][ty * 8 + 4];
            *(float4*)&b[0] = *(const float4*)&Bs[kk][tx * 8];
            *(float4*)&b[4] = *(const float4*)&Bs[kk][tx * 8 + 4];
#pragma unroll
            for (int r = 0; r < 8; ++r)
#pragma unroll
                for (int c = 0; c < 8; ++c)
                    acc[r][c] = fmaf(a[r], b[c], acc[r][c]);
        }
    }

    float bias[8];
    *(float4*)&bias[0] = *(const float4*)(Bv + cb + tx * 8);
    *(float4*)&bias[4] = *(const float4*)(Bv + cb + tx * 8 + 4);

#pragma unroll
    for (int r = 0; r < 8; ++r) {
        float4 o0, o1;
        o0.x = acc[r][0] + bias[0]; o0.y = acc[r][1] + bias[1];
        o0.z = acc[r][2] + bias[2]; o0.w = acc[r][3] + bias[3];
        o1.x = acc[r][4] + bias[4]; o1.y = acc[r][5] + bias[5];
        o1.z = acc[r][6] + bias[6]; o1.w = acc[r][7] + bias[7];
        float* dst = Xp + (size_t)(by * 128 + ty * 8 + r) * GCOLS + gate * HID + cb + tx * 8;
        *(float4*)(dst)     = o0;
        *(float4*)(dst + 4) = o1;
    }
}

// =================== Phase 2: 128 blocks x 256 threads (4 waves). Block b owns
// cols 8b..8b+7.
// CHANGE vs r10 (the single experiment this round): hb is PADDED so each
// block owns a PRIVATE 128B cache line (8 payload u32 + 24 pad; stride 32).
// r10 evidence: VALUBusy 9.3% x 6150cy/step == the ~600cy VALU work; ~5500cy
// is coherence wait. Old layout: 4 writers shared each line, each write an
// RFO against ~128 polling waves -> 4 serialized RFO+reshare cycles/line/step.
// New layout: ONE coalesced 32B publish per line per step = 1 RFO.
// Lane->k mapping preserved: lane l of wave w reads line bw=32w+(l>>1),
// 16B at (l&1)*4, giving k = 8*bw + 4*(l&1) + q = 256w + 4l + q (identical
// to r10's contiguous slice; MAC/fold/act code untouched).
// Tags now 6-bit (mask 0x3F): stale = tg-2 mod 64 != tg; poison 0xAA -> tag 42
// first awaited at s=41, line rewritten 21x before; injected value error drops
// 4x vs r10's 8-bit (<= 2^-17 rel) -- r10 absmax 3.9e-3 vs r5 1.95e-3 was the
// 8-bit tag error compounding through the recurrence.
__global__ __launch_bounds__(256, 1) void lstm_rec(
    const float* __restrict__ Wf, const float* __restrict__ Wi,
    const float* __restrict__ Wm, const float* __restrict__ Wo,
    const float* __restrict__ Xp,
    uint32_t* __restrict__ hb,     // 2 x 128 lines x 32 u32 (8 payload + 24 pad)
    float* __restrict__ out)
{
    const int b = blockIdx.x;      // 0..127
    const int t = threadIdx.x;     // 0..255
    const int w = t >> 6;          // wave id = k-slice id
    const int l = t & 63;          // lane
    const int j8 = b * 8;

    __shared__ float gsum[2][4][32];   // [step parity][wave][g*8+c]

    // publish h^(0)=0 with tag 1 into buffer 0 (word 0x1 = denormal ~ 0.0f)
    if (t < 8)
        __hip_atomic_store(&hb[b * 32 + t], 1u, __ATOMIC_RELAXED, __HIP_MEMORY_SCOPE_AGENT);

    const int kq = w * 256 + l * 4;    // this lane's 4 h-indices == its MAC k's
    // poll word-offset of those 4 h's in the padded layout:
    const int poff = (32 * w + (l >> 1)) * 32 + (l & 1) * 4;

    // weights wr[q][g][c] = W_h^g[kq+q][j8+c]  (128 floats/lane)
    const float* Wg[4] = { Wf, Wi, Wm, Wo };
    float wr[4][4][8];
#pragma unroll
    for (int g = 0; g < 4; ++g)
#pragma unroll
        for (int q = 0; q < 4; ++q) {
            const float* base = Wg[g] + (size_t)(INDIM + kq + q) * HID + j8;
            *(float4*)&wr[q][g][0] = *(const float4*)(base);
            *(float4*)&wr[q][g][4] = *(const float4*)(base + 4);
        }

    float cst = 0.f;               // cell state (lanes t<8 only)
    int budget = 1 << 20;          // poll budget: bug => wrong answer, not hang

    for (int s = 0; s < SEQ; ++s) {
        const uint32_t* src = hb + (size_t)(s & 1) * 4096;
        uint32_t*       dst = hb + (size_t)((s + 1) & 1) * 4096;
        const uint32_t tg = (uint32_t)(s + 1) & 0x3Fu;

        // prefetch Xp (independent of h): lane t<32 -> gate t>>3, col j8+(t&7)
        float xp = 0.f;
        if (t < 32) xp = Xp[(size_t)s * GCOLS + (size_t)(t >> 3) * HID + j8 + (t & 7)];

        // poll: ONE 16B device-scope load per lane per round
        const uint32_t* ap = src + poff;
        uint32_t p0, p1, p2, p3;
        for (;;) {
            u32x4 pv;
            asm volatile("global_load_dwordx4 %0, %1, off sc1\n\t"
                         "s_waitcnt vmcnt(0)"
                         : "=v"(pv) : "v"(ap) : "memory");
            p0 = pv.x; p1 = pv.y; p2 = pv.z; p3 = pv.w;
            uint32_t bad = ((p0 ^ tg) | (p1 ^ tg) | (p2 ^ tg) | (p3 ^ tg)) & 0x3Fu;
            if (__all(bad == 0)) break;
            if (--budget < 0) break;
            __builtin_amdgcn_s_sleep(1);   // ~64cy backoff
        }

        const float h0 = __uint_as_float(p0);
        const float h1 = __uint_as_float(p1);
        const float h2 = __uint_as_float(p2);
        const float h3 = __uint_as_float(p3);

        // 32 accumulators: A[g*8+c] = sum_q h_q * wr[q][g][c]
        float A[32];
#pragma unroll
        for (int g = 0; g < 4; ++g)
#pragma unroll
            for (int c = 0; c < 8; ++c)
                A[g * 8 + c] = fmaf(h0, wr[0][g][c],
                               fmaf(h1, wr[1][g][c],
                               fmaf(h2, wr[2][g][c], h3 * wr[3][g][c])));

        // fold 32 -> 1 acc/lane (index bits match lane bits); then butterfly 32
        const bool q0 = (l & 1) != 0, q1 = (l & 2) != 0, q2 = (l & 4) != 0,
                   q3 = (l & 8) != 0, q4 = (l & 16) != 0;
        float B[16];
#pragma unroll
        for (int i = 0; i < 16; ++i) {
            float snd = q0 ? A[2 * i] : A[2 * i + 1];
            float kp  = q0 ? A[2 * i + 1] : A[2 * i];
            B[i] = kp + __shfl_xor(snd, 1, 64);
        }
        float C[8];
#pragma unroll
        for (int i = 0; i < 8; ++i) {
            float snd = q1 ? B[2 * i] : B[2 * i + 1];
            float kp  = q1 ? B[2 * i + 1] : B[2 * i];
            C[i] = kp + __shfl_xor(snd, 2, 64);
        }
        float D[4];
#pragma unroll
        for (int i = 0; i < 4; ++i) {
            float snd = q2 ? C[2 * i] : C[2 * i + 1];
            float kp  = q2 ? C[2 * i + 1] : C[2 * i];
            D[i] = kp + __shfl_xor(snd, 4, 64);
        }
        float E2[2];
#pragma unroll
        for (int i = 0; i < 2; ++i) {
            float snd = q3 ? D[2 * i] : D[2 * i + 1];
            float kp  = q3 ? D[2 * i + 1] : D[2 * i];
            E2[i] = kp + __shfl_xor(snd, 8, 64);
        }
        {
            float snd = q4 ? E2[0] : E2[1];
            float kp  = q4 ? E2[1] : E2[0];
            float E = kp + __shfl_xor(snd, 16, 64);
            E += __shfl_xor(E, 32, 64);
            if (l < 32) gsum[s & 1][w][l] = E;   // lane l owns (g,c)=(l>>3,l&7)
        }
        __syncthreads();   // the step's only barrier

        if (t < 32) {      // wave 0 lanes 0..31: parallel activations
            float pre = gsum[s & 1][0][t] + gsum[s & 1][1][t]
                      + gsum[s & 1][2][t] + gsum[s & 1][3][t] + xp;
            const bool isM = ((t >> 3) == 2);              // gate m = tanh
            float arg = isM ? 2.f * pre : pre;
            float S = 1.f / (1.f + expf(-arg));
            float Aact = isM ? 2.f * S - 1.f : S;          // tanh(x)=2*sig(2x)-1

            float i_ = __shfl(Aact, 8  + (t & 7), 64);
            float m_ = __shfl(Aact, 16 + (t & 7), 64);
            float o_ = __shfl(Aact, 24 + (t & 7), 64);

            if (t < 8) {   // lane t: col j8+t (gate f -> Aact is forget act)
                cst = fmaf(Aact, cst, i_ * m_);
                float th = 2.f / (1.f + expf(-2.f * cst)) - 1.f;  // tanh, NaN-safe
                float hv = o_ * th;
                uint32_t word = (__float_as_uint(hv) & ~0x3Fu) | ((tg + 1) & 0x3Fu);
                out[(size_t)s * HID + j8 + t] = __uint_as_float(word);
                // 8 lanes, contiguous 32B in the block's PRIVATE line: one
                // coalesced store transaction = one RFO per line per step.
                __hip_atomic_store(&dst[b * 32 + t], word,
                                   __ATOMIC_RELAXED, __HIP_MEMORY_SCOPE_AGENT);
            }
        }
        // gsum cross-step race-free: parity-buffered; a wave's step-(s+2)
        // rewrite of gsum[s&1] is behind the step-(s+1) barrier, which wave 0
        // reaches only after finishing this tail's reads.
    }
}

extern "C" void kernel_launch(void* const* d_in, const int* in_sizes, int n_in,
                              void* d_out, int out_size, void* d_ws, size_t ws_size,
                              hipStream_t stream) {
    const float* batch = (const float*)d_in[0];
    const float* Wf = (const float*)d_in[1]; const float* Bf = (const float*)d_in[2];
    const float* Wi = (const float*)d_in[3]; const float* Bi = (const float*)d_in[4];
    const float* Wm = (const float*)d_in[5]; const float* Bm = (const float*)d_in[6];
    const float* Wo = (const float*)d_in[7]; const float* Bo = (const float*)d_in[8];
    float* out = (float*)d_out;

    float* Xp = (float*)d_ws;                                   // 64 MB
    uint32_t* hb =
        (uint32_t*)((char*)d_ws + (size_t)SEQ * GCOLS * sizeof(float)); // 32 KB padded

    xproj_gemm<<<dim3(32, 32), 256, 0, stream>>>(batch, Wf, Bf, Wi, Bi, Wm, Bm, Wo, Bo, Xp);

    // 128 blocks / 256 CUs: co-resident by construction.
    lstm_rec<<<dim3(128), 256, 0, stream>>>(Wf, Wi, Wm, Wo, Xp, hb, out);
}